// Round 2
// baseline (425.586 us; speedup 1.0000x reference)
//
#include <hip/hip_runtime.h>
#include <hip/hip_fp16.h>
#include <math.h>

// ---------------------------------------------------------------------------
// ADCGNN amazon: N=50000, E=1.6M, IN=128, H=64, C=2, K=3
// All node features AoS. Gathered operands hs/u1s are fp16 rows (128 B).
//
// R5: fp16 gather rows (FETCH halved; time ~flat) -> gather is bound by
//     scattered-load INSTRUCTION count x latency, not bytes.
// R6 (this round): re-tile gather to 8 lanes/row (dwordx4 of f16), 8 subs
//     per wave -> 8 rows per load instruction, 32 edges per iteration.
//     Row-load instrs/edge: 0.25 -> 0.125. fp32 accumulate unchanged.
//
// Pipeline:
//   build: bucket_count -> bucket_scan -> bucket_scatter -> csr_build
//   dense1:    h1 = relu(X@W1+b1)                     (thread/node, AoS)
//   dense2res: h, hs=f16(h*dinv), res=h@Wres+bres, th=h.Wattn
//   spmm1:     u1 = dinv*(A^T hs), u1s = f16(u1*dinv), ta = u1.Wattn
//   tail:      wave/node: gather u2 (regs only) -> softmax -> Wf1/Wf2 ->
//              W3 -> W4 -> logits. u2 never hits HBM; wave-GEMV via shfl.
// ---------------------------------------------------------------------------

#define BSHIFT 7
#define BNODES 128
#define BMAX   512
#define EPT    32
#define CHUNK  (256 * EPT)
#define CAP    8192

__device__ __forceinline__ void fma4(float4& acc, float s, const float4 w) {
    acc.x += s * w.x; acc.y += s * w.y; acc.z += s * w.z; acc.w += s * w.w;
}

// pack 4 floats -> 4 halves carried in a float2
__device__ __forceinline__ float2 pack_half4(float x, float y, float z, float w) {
    union { __half2 h[2]; float2 f; } u;
    u.h[0] = __floats2half2_rn(x, y);
    u.h[1] = __floats2half2_rn(z, w);
    return u.f;
}

// pack 8 floats -> 8 halves carried in a float4
__device__ __forceinline__ float4 pack_half8(const float* r) {
    union { __half2 h[4]; float4 f; } u;
    u.h[0] = __floats2half2_rn(r[0], r[1]);
    u.h[1] = __floats2half2_rn(r[2], r[3]);
    u.h[2] = __floats2half2_rn(r[4], r[5]);
    u.h[3] = __floats2half2_rn(r[6], r[7]);
    return u.f;
}

// unpack 8 halves (in a float4) and accumulate into float[8] (fp32)
__device__ __forceinline__ void acch8(float* a, float4 p) {
    union { float4 f; __half2 h[4]; } u; u.f = p;
    #pragma unroll
    for (int t = 0; t < 4; t++) {
        float2 v = __half22float2(u.h[t]);
        a[2 * t]     += v.x;
        a[2 * t + 1] += v.y;
    }
}

// ----------------------------- graph build ---------------------------------

__global__ __launch_bounds__(256) void bucket_count_k(const int* __restrict__ dst,
                                                      int* __restrict__ bucketCount,
                                                      int E, int B) {
    __shared__ int cnt[BMAX];
    for (int i = threadIdx.x; i < B; i += 256) cnt[i] = 0;
    __syncthreads();
    int base = blockIdx.x * CHUNK;
    #pragma unroll
    for (int t = 0; t < EPT; t++) {
        int e = base + t * 256 + threadIdx.x;
        if (e < E) atomicAdd(&cnt[dst[e] >> BSHIFT], 1);
    }
    __syncthreads();
    for (int i = threadIdx.x; i < B; i += 256)
        if (cnt[i] > 0) atomicAdd(&bucketCount[i], cnt[i]);
}

__global__ __launch_bounds__(64) void bucket_scan_k(const int* __restrict__ bucketCount,
                                                    int* __restrict__ bucketPtr,
                                                    int* __restrict__ bucketCursor,
                                                    int* __restrict__ rowPtr,
                                                    int B, int N, int E) {
    int lane = threadIdx.x;
    const int PT = (BMAX + 63) / 64;
    int v[PT]; int s = 0;
    #pragma unroll
    for (int t = 0; t < PT; t++) {
        int i = lane * PT + t;
        v[t] = (i < B) ? bucketCount[i] : 0;
        s += v[t];
    }
    int x = s;
    #pragma unroll
    for (int off = 1; off < 64; off <<= 1) {
        int y = __shfl_up(x, off, 64);
        if (lane >= off) x += y;
    }
    int run = x - s;
    #pragma unroll
    for (int t = 0; t < PT; t++) {
        int i = lane * PT + t;
        if (i < B) { bucketPtr[i] = run; bucketCursor[i] = run; }
        run += v[t];
    }
    if (lane == 63) bucketPtr[B] = x;
    if (lane == 0) rowPtr[N] = E;
}

__global__ __launch_bounds__(256) void bucket_scatter_k(const int* __restrict__ src,
                                                        const int* __restrict__ dst,
                                                        int* __restrict__ bucketCursor,
                                                        int* __restrict__ ebuf,
                                                        int E, int B) {
    __shared__ int cnt[BMAX];
    __shared__ int base[BMAX];
    __shared__ int cur[BMAX];
    for (int i = threadIdx.x; i < B; i += 256) { cnt[i] = 0; cur[i] = 0; }
    __syncthreads();
    int cbase = blockIdx.x * CHUNK;
    int d[EPT];
    #pragma unroll
    for (int t = 0; t < EPT; t++) {
        int e = cbase + t * 256 + threadIdx.x;
        d[t] = (e < E) ? dst[e] : -1;
        if (d[t] >= 0) atomicAdd(&cnt[d[t] >> BSHIFT], 1);
    }
    __syncthreads();
    for (int i = threadIdx.x; i < B; i += 256)
        if (cnt[i] > 0) base[i] = atomicAdd(&bucketCursor[i], cnt[i]);
    __syncthreads();
    #pragma unroll
    for (int t = 0; t < EPT; t++) {
        int e = cbase + t * 256 + threadIdx.x;
        if (d[t] >= 0) {
            int b = d[t] >> BSHIFT;
            int c = atomicAdd(&cur[b], 1);
            int pack = (src[e] & 0xFFFF) | ((d[t] & (BNODES - 1)) << 16);
            ebuf[base[b] + c] = pack;
        }
    }
}

__global__ __launch_bounds__(256) void csr_build_k(const int* __restrict__ ebuf,
                                                   const int* __restrict__ bucketPtr,
                                                   int* __restrict__ rowPtr,
                                                   float* __restrict__ dinv,
                                                   int* __restrict__ srcSorted,
                                                   int N) {
    __shared__ int deg[BNODES];
    __shared__ int rp[BNODES + 1];
    __shared__ int cur[BNODES];
    __shared__ int stage[CAP];
    int b = blockIdx.x;
    int nodeBase = b << BSHIFT;
    int nNodes = min(BNODES, N - nodeBase);
    int eBase = bucketPtr[b];
    int eCnt = bucketPtr[b + 1] - eBase;
    for (int i = threadIdx.x; i < BNODES; i += 256) deg[i] = 0;
    __syncthreads();
    for (int i = threadIdx.x; i < eCnt; i += 256)
        atomicAdd(&deg[(ebuf[eBase + i] >> 16) & (BNODES - 1)], 1);
    __syncthreads();
    if (threadIdx.x < 64) {
        int lane = threadIdx.x;
        int d0 = deg[2 * lane], d1 = deg[2 * lane + 1];
        int s = d0 + d1;
        int x = s;
        #pragma unroll
        for (int off = 1; off < 64; off <<= 1) {
            int y = __shfl_up(x, off, 64);
            if (lane >= off) x += y;
        }
        int ex = x - s;
        rp[2 * lane] = ex;
        rp[2 * lane + 1] = ex + d0;
        cur[2 * lane] = ex;
        cur[2 * lane + 1] = ex + d0;
        if (lane == 63) rp[BNODES] = x;
    }
    __syncthreads();
    for (int j = threadIdx.x; j < nNodes; j += 256) {
        rowPtr[nodeBase + j] = eBase + rp[j];
        int dg = deg[j];
        dinv[nodeBase + j] = rsqrtf((float)(dg > 1 ? dg : 1));
    }
    if (eCnt <= CAP) {
        for (int i = threadIdx.x; i < eCnt; i += 256) {
            int p = ebuf[eBase + i];
            int ld = (p >> 16) & (BNODES - 1);
            int pos = atomicAdd(&cur[ld], 1);
            stage[pos] = p & 0xFFFF;
        }
        __syncthreads();
        for (int i = threadIdx.x; i < eCnt; i += 256)
            srcSorted[eBase + i] = stage[i];
    } else {
        for (int i = threadIdx.x; i < eCnt; i += 256) {
            int p = ebuf[eBase + i];
            int ld = (p >> 16) & (BNODES - 1);
            int pos = atomicAdd(&cur[ld], 1);
            srcSorted[eBase + pos] = p & 0xFFFF;
        }
    }
}

// ----------------------------- dense1 --------------------------------------
// Thread per node, AoS in/out, LDS-bounced contiguous output writes.

#define D1_BLK 128
#define D1_PAD 68

__global__ __launch_bounds__(D1_BLK) void dense1_k(const float* __restrict__ Xg,
                                                   const float* __restrict__ W1,
                                                   const float* __restrict__ b1,
                                                   float* __restrict__ h1, int N) {
    __shared__ float lds[D1_BLK * D1_PAD];
    int n0 = blockIdx.x * D1_BLK;
    int n = n0 + threadIdx.x;
    bool act = (n < N);
    const float4* W = (const float4*)W1;
    const float4* B = (const float4*)b1;
    float4 acc[16];
    #pragma unroll
    for (int j = 0; j < 16; j++) acc[j] = B[j];
    if (act) {
        const float4* X = (const float4*)Xg + (size_t)n * 32;
        float4 a = X[0];
        #pragma unroll 1
        for (int kc = 0; kc < 32; kc++) {
            float4 an = a;
            if (kc + 1 < 32) an = X[kc + 1];
            const float4* wrow = W + kc * 64;
            #pragma unroll
            for (int j = 0; j < 16; j++) {
                fma4(acc[j], a.x, wrow[j]);
                fma4(acc[j], a.y, wrow[16 + j]);
                fma4(acc[j], a.z, wrow[32 + j]);
                fma4(acc[j], a.w, wrow[48 + j]);
            }
            a = an;
        }
    }
    float* myrow = &lds[threadIdx.x * D1_PAD];
    #pragma unroll
    for (int j = 0; j < 16; j++) {
        float4 v = acc[j];
        *(float4*)&myrow[4 * j] = make_float4(fmaxf(v.x, 0.f), fmaxf(v.y, 0.f),
                                              fmaxf(v.z, 0.f), fmaxf(v.w, 0.f));
    }
    __syncthreads();
    float4* o4 = (float4*)h1;
    #pragma unroll
    for (int r = 0; r < 16; r++) {
        int idx = r * D1_BLK + threadIdx.x;
        int row = idx >> 4, col = idx & 15;
        int gn = n0 + row;
        if (gn < N) o4[(size_t)gn * 16 + col] = *(float4*)&lds[row * D1_PAD + col * 4];
    }
}

// ----------------------------- dense2res -----------------------------------
// Thread per node. Outputs h (fp32), hs (=f16(h*dinv)), res via LDS bounce;
// th = h.Wattn.

#define D2_BLK 128
#define D2_PAD 68

__global__ __launch_bounds__(D2_BLK) void dense2res_k(const float* __restrict__ h1,
                                                      const float* __restrict__ W2,
                                                      const float* __restrict__ b2,
                                                      const float* __restrict__ Wres,
                                                      const float* __restrict__ bres,
                                                      const float* __restrict__ Wattn,
                                                      const float* __restrict__ dinv,
                                                      float* __restrict__ hg,
                                                      float2* __restrict__ hs2,
                                                      float* __restrict__ resg,
                                                      float* __restrict__ thv, int N) {
    __shared__ float lds[D2_BLK * D2_PAD];
    int n0 = blockIdx.x * D2_BLK;
    int n = n0 + threadIdx.x;
    bool act = (n < N);
    const float4* W = (const float4*)W2;
    const float4* B = (const float4*)b2;
    float4 acc[16];
    #pragma unroll
    for (int j = 0; j < 16; j++) acc[j] = B[j];
    if (act) {
        const float4* X = (const float4*)h1 + (size_t)n * 16;
        float4 a = X[0];
        #pragma unroll 1
        for (int kc = 0; kc < 16; kc++) {
            float4 an = a;
            if (kc + 1 < 16) an = X[kc + 1];
            const float4* wrow = W + kc * 64;
            #pragma unroll
            for (int j = 0; j < 16; j++) {
                fma4(acc[j], a.x, wrow[j]);
                fma4(acc[j], a.y, wrow[16 + j]);
                fma4(acc[j], a.z, wrow[32 + j]);
                fma4(acc[j], a.w, wrow[48 + j]);
            }
            a = an;
        }
    }
    // relu; stage h; attention score
    const float4* Wa = (const float4*)Wattn;
    float th = 0.f;
    float* myrow = &lds[threadIdx.x * D2_PAD];
    #pragma unroll
    for (int j = 0; j < 16; j++) {
        float4 v = acc[j];
        v.x = fmaxf(v.x, 0.f); v.y = fmaxf(v.y, 0.f);
        v.z = fmaxf(v.z, 0.f); v.w = fmaxf(v.w, 0.f);
        acc[j] = v;
        *(float4*)&myrow[4 * j] = v;
        float4 w = Wa[j];
        th += v.x * w.x + v.y * w.y + v.z * w.z + v.w * w.w;
    }
    if (act) thv[n] = th;
    __syncthreads();
    // coop contiguous writes of h (fp32) and hs (f16 packed)
    float4* h4 = (float4*)hg;
    #pragma unroll
    for (int r = 0; r < 16; r++) {
        int idx = r * D2_BLK + threadIdx.x;
        int row = idx >> 4, col = idx & 15;
        int gn = n0 + row;
        if (gn < N) {
            float4 v = *(float4*)&lds[row * D2_PAD + col * 4];
            h4[(size_t)gn * 16 + col] = v;
            float di = dinv[gn];
            hs2[(size_t)gn * 16 + col] =
                pack_half4(v.x * di, v.y * di, v.z * di, v.w * di);
        }
    }
    // res = h @ Wres + bres (h still in regs)
    const float4* WR = (const float4*)Wres;
    const float4* BR = (const float4*)bres;
    float4 acc2[16];
    #pragma unroll
    for (int j = 0; j < 16; j++) acc2[j] = BR[j];
    #pragma unroll 1
    for (int kc = 0; kc < 16; kc++) {
        float4 a2 = acc[kc];
        const float4* wrow = WR + kc * 64;
        #pragma unroll
        for (int j = 0; j < 16; j++) {
            fma4(acc2[j], a2.x, wrow[j]);
            fma4(acc2[j], a2.y, wrow[16 + j]);
            fma4(acc2[j], a2.z, wrow[32 + j]);
            fma4(acc2[j], a2.w, wrow[48 + j]);
        }
    }
    __syncthreads();   // h/hs coop reads done before overwrite
    #pragma unroll
    for (int j = 0; j < 16; j++) *(float4*)&myrow[4 * j] = acc2[j];
    __syncthreads();
    float4* r4 = (float4*)resg;
    #pragma unroll
    for (int r = 0; r < 16; r++) {
        int idx = r * D2_BLK + threadIdx.x;
        int row = idx >> 4, col = idx & 15;
        int gn = n0 + row;
        if (gn < N) r4[(size_t)gn * 16 + col] = *(float4*)&lds[row * D2_PAD + col * 4];
    }
}

// ----------------------------- SPMM (spmm1) --------------------------------
// Wave per node (4/block). 8 lanes per f16 row (dwordx4 loads) -> 8 rows per
// load instruction, 32 edges per main iteration, 4 independent chains.
// fp32 accum. Outputs u1 (fp32 AoS), u1s (f16), ta = u1.Wattn.

__global__ __launch_bounds__(256) void spmm_k(const float4* __restrict__ xs,
                                              const int* __restrict__ srcs,
                                              const int* __restrict__ rowPtr,
                                              const float* __restrict__ dinv,
                                              const float* __restrict__ Wattn,
                                              float4* __restrict__ u,
                                              float4* __restrict__ us,
                                              float* __restrict__ tav, int N) {
    int node = (blockIdx.x * 256 + threadIdx.x) >> 6;
    if (node >= N) return;
    int lane = threadIdx.x & 63;
    int sub = lane >> 3;      // 0..7: which edge within the group of 8
    int q = lane & 7;         // 0..7: 16-byte chunk within the 128 B row
    int s0 = rowPtr[node], s1 = rowPtr[node + 1];
    float acc0[8], acc1[8], acc2[8], acc3[8];
    #pragma unroll
    for (int t = 0; t < 8; t++) { acc0[t] = 0.f; acc1[t] = 0.f; acc2[t] = 0.f; acc3[t] = 0.f; }
    int i = s0 + sub;
    for (; i + 24 < s1; i += 32) {
        int sA = srcs[i];
        int sB = srcs[i + 8];
        int sC = srcs[i + 16];
        int sD = srcs[i + 24];
        float4 vA = xs[(size_t)sA * 8 + q];
        float4 vB = xs[(size_t)sB * 8 + q];
        float4 vC = xs[(size_t)sC * 8 + q];
        float4 vD = xs[(size_t)sD * 8 + q];
        acch8(acc0, vA); acch8(acc1, vB); acch8(acc2, vC); acch8(acc3, vD);
    }
    for (; i + 8 < s1; i += 16) {
        int sA = srcs[i];
        int sB = srcs[i + 8];
        float4 vA = xs[(size_t)sA * 8 + q];
        float4 vB = xs[(size_t)sB * 8 + q];
        acch8(acc0, vA); acch8(acc1, vB);
    }
    if (i < s1) {
        float4 vA = xs[(size_t)srcs[i] * 8 + q];
        acch8(acc0, vA);
    }
    float s[8];
    #pragma unroll
    for (int t = 0; t < 8; t++) s[t] = (acc0[t] + acc1[t]) + (acc2[t] + acc3[t]);
    #pragma unroll
    for (int m = 8; m < 64; m <<= 1) {
        #pragma unroll
        for (int t = 0; t < 8; t++) s[t] += __shfl_xor(s[t], m, 64);
    }
    if (sub == 0) {
        float di = dinv[node];
        float r[8];
        #pragma unroll
        for (int t = 0; t < 8; t++) r[t] = s[t] * di;
        u[(size_t)node * 16 + q * 2]     = make_float4(r[0], r[1], r[2], r[3]);
        u[(size_t)node * 16 + q * 2 + 1] = make_float4(r[4], r[5], r[6], r[7]);
        float rs[8];
        #pragma unroll
        for (int t = 0; t < 8; t++) rs[t] = r[t] * di;
        us[(size_t)node * 8 + q] = pack_half8(rs);
        const float4* Wa4 = (const float4*)Wattn;
        float4 w0 = Wa4[q * 2], w1 = Wa4[q * 2 + 1];
        float p = r[0] * w0.x + r[1] * w0.y + r[2] * w0.z + r[3] * w0.w
                + r[4] * w1.x + r[5] * w1.y + r[6] * w1.z + r[7] * w1.w;
        #pragma unroll
        for (int m = 1; m < 8; m <<= 1) p += __shfl_xor(p, m, 64);
        if (lane == 0) tav[node] = p;
    }
}

// ----------------------------- fused spmm2 + tail --------------------------
// Wave per node (4/block). Same 8-lane-per-row gather; u2 lives only in
// registers/LDS. Lane j owns feature j after LDS bounce; wave-GEMV via shfl.

#define TL_PAD 68

__global__ __launch_bounds__(256) void tail_k(const float4* __restrict__ u1s,
                                              const int* __restrict__ srcs,
                                              const int* __restrict__ rowPtr,
                                              const float* __restrict__ dinv,
                                              const float* __restrict__ hg,
                                              const float* __restrict__ u1g,
                                              const float* __restrict__ resg,
                                              const float* __restrict__ thv,
                                              const float* __restrict__ tav,
                                              const float* __restrict__ Wattn,
                                              const float* __restrict__ battn,
                                              const float* __restrict__ Wf1,
                                              const float* __restrict__ bf1,
                                              const float* __restrict__ Wf2,
                                              const float* __restrict__ bf2,
                                              const float* __restrict__ W3,
                                              const float* __restrict__ b3,
                                              const float* __restrict__ W4,
                                              const float* __restrict__ b4,
                                              float2* __restrict__ out, int N) {
    __shared__ float lds[4 * TL_PAD];
    int w = threadIdx.x >> 6;
    int lane = threadIdx.x & 63;
    int node = blockIdx.x * 4 + w;
    bool active = (node < N);
    int sub = lane >> 3, q = lane & 7;
    if (active) {
        int s0 = rowPtr[node], s1 = rowPtr[node + 1];
        float acc0[8], acc1[8], acc2[8], acc3[8];
        #pragma unroll
        for (int t = 0; t < 8; t++) { acc0[t] = 0.f; acc1[t] = 0.f; acc2[t] = 0.f; acc3[t] = 0.f; }
        int i = s0 + sub;
        for (; i + 24 < s1; i += 32) {
            int sA = srcs[i];
            int sB = srcs[i + 8];
            int sC = srcs[i + 16];
            int sD = srcs[i + 24];
            float4 vA = u1s[(size_t)sA * 8 + q];
            float4 vB = u1s[(size_t)sB * 8 + q];
            float4 vC = u1s[(size_t)sC * 8 + q];
            float4 vD = u1s[(size_t)sD * 8 + q];
            acch8(acc0, vA); acch8(acc1, vB); acch8(acc2, vC); acch8(acc3, vD);
        }
        for (; i + 8 < s1; i += 16) {
            int sA = srcs[i];
            int sB = srcs[i + 8];
            float4 vA = u1s[(size_t)sA * 8 + q];
            float4 vB = u1s[(size_t)sB * 8 + q];
            acch8(acc0, vA); acch8(acc1, vB);
        }
        if (i < s1) {
            float4 vA = u1s[(size_t)srcs[i] * 8 + q];
            acch8(acc0, vA);
        }
        float s[8];
        #pragma unroll
        for (int t = 0; t < 8; t++) s[t] = (acc0[t] + acc1[t]) + (acc2[t] + acc3[t]);
        #pragma unroll
        for (int m = 8; m < 64; m <<= 1) {
            #pragma unroll
            for (int t = 0; t < 8; t++) s[t] += __shfl_xor(s[t], m, 64);
        }
        if (sub == 0) {
            float di = dinv[node];
            float* dp = &lds[w * TL_PAD + q * 8];
            *(float4*)&dp[0] = make_float4(s[0] * di, s[1] * di, s[2] * di, s[3] * di);
            *(float4*)&dp[4] = make_float4(s[4] * di, s[5] * di, s[6] * di, s[7] * di);
        }
    }
    __syncthreads();
    if (!active) return;
    float u2j = lds[w * TL_PAD + lane];                  // feature j = lane
    float hj = hg[(size_t)node * 64 + lane];
    float u1j = u1g[(size_t)node * 64 + lane];
    float resj = resg[(size_t)node * 64 + lane];
    // tb = u2 . Wattn
    float tb = u2j * Wattn[lane];
    #pragma unroll
    for (int m = 1; m < 64; m <<= 1) tb += __shfl_xor(tb, m, 64);
    float th = thv[node], ta = tav[node], ba = battn[0];
    float s0 = 0.75f * th + 1.5f * ta + 0.75f * tb + ba;
    float s1 = 1.5f * th - 1.5f * tb + ba;
    float s2 = 0.75f * th - 1.5f * ta + 0.75f * tb + ba;
    float mx = fmaxf(s0, fmaxf(s1, s2));
    float e0 = expf(s0 - mx), e1 = expf(s1 - mx), e2 = expf(s2 - mx);
    float inv = 1.f / (e0 + e1 + e2);
    float w0 = e0 * inv, w1 = e1 * inv, w2 = e2 * inv;
    float ca = 0.75f * w0 + 1.5f * w1 + 0.75f * w2;
    float cb = 1.5f * (w0 - w2);
    float cc = 0.75f * w0 - 1.5f * w1 + 0.75f * w2;
    float afj = ca * hj + cb * u1j + cc * u2j;
    // t = relu([af | h] @ Wf1 + bf1)  (wave-GEMV, shfl-broadcast inputs)
    float t = bf1[lane];
    #pragma unroll 4
    for (int k = 0; k < 64; k++) {
        float afk = __shfl(afj, k, 64);
        float hk = __shfl(hj, k, 64);
        t += afk * Wf1[k * 64 + lane] + hk * Wf1[(64 + k) * 64 + lane];
    }
    t = fmaxf(t, 0.f);
    float fwacc = t * Wf2[lane];
    #pragma unroll
    for (int m = 1; m < 64; m <<= 1) fwacc += __shfl_xor(fwacc, m, 64);
    float fw = 1.f / (1.f + expf(-(fwacc + bf2[0])));
    // fused = 0.1*fw*af + (1-fw)*h + 0.8*res   (mean_fused == h exactly)
    float fj = 0.1f * fw * afj + (1.f - fw) * hj + 0.8f * resj;
    float g = b3[lane];
    #pragma unroll 4
    for (int k = 0; k < 64; k++) {
        float fk = __shfl(fj, k, 64);
        g += fk * W3[k * 64 + lane];
    }
    g = fmaxf(g, 0.f);
    float2 w4 = ((const float2*)W4)[lane];
    float l0 = g * w4.x, l1 = g * w4.y;
    #pragma unroll
    for (int m = 1; m < 64; m <<= 1) {
        l0 += __shfl_xor(l0, m, 64);
        l1 += __shfl_xor(l1, m, 64);
    }
    if (lane == 0) out[node] = make_float2(l0 + b4[0], l1 + b4[1]);
}

// ----------------------------- launch --------------------------------------

extern "C" void kernel_launch(void* const* d_in, const int* in_sizes, int n_in,
                              void* d_out, int out_size, void* d_ws, size_t ws_size,
                              hipStream_t stream) {
    const float* in_feat = (const float*)d_in[0];
    const int*   src     = (const int*)d_in[1];
    const int*   dst     = (const int*)d_in[2];
    const float* W1   = (const float*)d_in[3];
    const float* b1   = (const float*)d_in[4];
    const float* W2   = (const float*)d_in[5];
    const float* b2   = (const float*)d_in[6];
    const float* Wres = (const float*)d_in[7];
    const float* bres = (const float*)d_in[8];
    const float* Wattn = (const float*)d_in[9];
    const float* battn = (const float*)d_in[10];
    const float* Wf1  = (const float*)d_in[11];
    const float* bf1  = (const float*)d_in[12];
    const float* Wf2  = (const float*)d_in[13];
    const float* bf2  = (const float*)d_in[14];
    const float* W3   = (const float*)d_in[15];
    const float* b3   = (const float*)d_in[16];
    const float* W4   = (const float*)d_in[17];
    const float* b4   = (const float*)d_in[18];

    const int N = in_sizes[0] / 128;
    const int E = in_sizes[1];
    const int B = (N + BNODES - 1) >> BSHIFT;

    char* p = (char*)d_ws;
    auto take = [&](size_t bytes) -> char* {
        char* r = p;
        p += (bytes + 255) & ~(size_t)255;
        return r;
    };
    int*   bucketCount  = (int*)take((size_t)(B + 1) * 4);
    int*   bucketPtr    = (int*)take((size_t)(B + 1) * 4);
    int*   bucketCursor = (int*)take((size_t)(B + 1) * 4);
    int*   rowPtr       = (int*)take((size_t)(N + 1) * 4);
    float* dinv         = (float*)take((size_t)N * 4);
    int*   srcSorted    = (int*)take((size_t)E * 4);
    float* thv          = (float*)take((size_t)N * 4);
    float* tav          = (float*)take((size_t)N * 4);
    float* h1  = (float*)take((size_t)N * 256);
    float* h   = (float*)take((size_t)N * 256);
    float* hs  = (float*)take((size_t)N * 128);   // f16 packed, 64 halves/row
    float* res = (float*)take((size_t)N * 256);
    float* u1  = (float*)take((size_t)N * 256);
    float* u1s = (float*)take((size_t)N * 128);   // f16 packed
    int*   ebuf = (int*)h1;   // dead before dense1 writes h1 (stream order)

    int eb = (E + CHUNK - 1) / CHUNK;
    int d1b = (N + D1_BLK - 1) / D1_BLK;
    int d2b = (N + D2_BLK - 1) / D2_BLK;
    int spb = (N * 64 + 255) / 256;
    int tlb = (N + 3) / 4;

    hipMemsetAsync(bucketCount, 0, (size_t)B * 4, stream);
    bucket_count_k<<<eb, 256, 0, stream>>>(dst, bucketCount, E, B);
    bucket_scan_k<<<1, 64, 0, stream>>>(bucketCount, bucketPtr, bucketCursor,
                                        rowPtr, B, N, E);
    bucket_scatter_k<<<eb, 256, 0, stream>>>(src, dst, bucketCursor, ebuf, E, B);
    csr_build_k<<<B, 256, 0, stream>>>(ebuf, bucketPtr, rowPtr, dinv, srcSorted, N);

    dense1_k<<<d1b, D1_BLK, 0, stream>>>(in_feat, W1, b1, h1, N);
    dense2res_k<<<d2b, D2_BLK, 0, stream>>>(h1, W2, b2, Wres, bres, Wattn, dinv,
                                            h, (float2*)hs, res, thv, N);

    spmm_k<<<spb, 256, 0, stream>>>((const float4*)hs, srcSorted, rowPtr, dinv,
                                    Wattn, (float4*)u1, (float4*)u1s, tav, N);

    tail_k<<<tlb, 256, 0, stream>>>((const float4*)u1s, srcSorted, rowPtr, dinv,
                                    h, u1, res, thv, tav, Wattn, battn,
                                    Wf1, bf1, Wf2, bf2, W3, b3, W4, b4,
                                    (float2*)d_out, N);
}

// Round 3
// 393.816 us; speedup vs baseline: 1.0807x; 1.0807x over previous
//
#include <hip/hip_runtime.h>
#include <hip/hip_fp16.h>
#include <math.h>

// ---------------------------------------------------------------------------
// ADCGNN amazon: N=50000, E=1.6M, IN=128, H=64, C=2, K=3
// All node features AoS. Gathered operands hs/u1s are fp16 rows (128 B).
//
// R5: fp16 gather rows (FETCH halved; time flat) -> gather not byte-bound.
// R6: 8-lane/row retile (instrs halved; time +9%, occ 83->64) -> gather not
//     instruction-bound either. REVERTED.
// R7 (this round): the dense tail was issuing 192 ds_bpermute/node (dynamic
//     __shfl broadcasts) on the LDS pipe + a needless __syncthreads coupling
//     the block's 4 waves. Fix: wave-private LDS (no barrier) + v_readlane
//     broadcasts (VALU, result in SGPR) for the GEMV loops.
//
// Pipeline:
//   build: bucket_count -> bucket_scan -> bucket_scatter -> csr_build
//   dense1:    h1 = relu(X@W1+b1)                     (thread/node, AoS)
//   dense2res: h, hs=f16(h*dinv), res=h@Wres+bres, th=h.Wattn
//   spmm1:     u1 = dinv*(A^T hs), u1s = f16(u1*dinv), ta = u1.Wattn
//   tail:      wave/node: gather u2 (regs/LDS only) -> softmax -> Wf1/Wf2 ->
//              W3 -> W4 -> logits. No block barrier; readlane wave-GEMVs.
// ---------------------------------------------------------------------------

#define BSHIFT 7
#define BNODES 128
#define BMAX   512
#define EPT    32
#define CHUNK  (256 * EPT)
#define CAP    8192

__device__ __forceinline__ void fma4(float4& acc, float s, const float4 w) {
    acc.x += s * w.x; acc.y += s * w.y; acc.z += s * w.z; acc.w += s * w.w;
}

// wave-uniform broadcast of lane k's value via v_readlane (VALU, -> SGPR)
__device__ __forceinline__ float bcast(float v, int k) {
    return __uint_as_float(__builtin_amdgcn_readlane(__float_as_uint(v), k));
}

// pack 4 floats -> 4 halves carried in a float2
__device__ __forceinline__ float2 pack_half4(float x, float y, float z, float w) {
    union { __half2 h[2]; float2 f; } u;
    u.h[0] = __floats2half2_rn(x, y);
    u.h[1] = __floats2half2_rn(z, w);
    return u.f;
}

// unpack 4 halves (in a float2) and accumulate into a float4 (fp32)
__device__ __forceinline__ void acch4(float4& a, float2 p) {
    union { float2 f; __half2 h[2]; } u; u.f = p;
    float2 lo = __half22float2(u.h[0]);
    float2 hi = __half22float2(u.h[1]);
    a.x += lo.x; a.y += lo.y; a.z += hi.x; a.w += hi.y;
}

// ----------------------------- graph build ---------------------------------

__global__ __launch_bounds__(256) void bucket_count_k(const int* __restrict__ dst,
                                                      int* __restrict__ bucketCount,
                                                      int E, int B) {
    __shared__ int cnt[BMAX];
    for (int i = threadIdx.x; i < B; i += 256) cnt[i] = 0;
    __syncthreads();
    int base = blockIdx.x * CHUNK;
    #pragma unroll
    for (int t = 0; t < EPT; t++) {
        int e = base + t * 256 + threadIdx.x;
        if (e < E) atomicAdd(&cnt[dst[e] >> BSHIFT], 1);
    }
    __syncthreads();
    for (int i = threadIdx.x; i < B; i += 256)
        if (cnt[i] > 0) atomicAdd(&bucketCount[i], cnt[i]);
}

__global__ __launch_bounds__(64) void bucket_scan_k(const int* __restrict__ bucketCount,
                                                    int* __restrict__ bucketPtr,
                                                    int* __restrict__ bucketCursor,
                                                    int* __restrict__ rowPtr,
                                                    int B, int N, int E) {
    int lane = threadIdx.x;
    const int PT = (BMAX + 63) / 64;
    int v[PT]; int s = 0;
    #pragma unroll
    for (int t = 0; t < PT; t++) {
        int i = lane * PT + t;
        v[t] = (i < B) ? bucketCount[i] : 0;
        s += v[t];
    }
    int x = s;
    #pragma unroll
    for (int off = 1; off < 64; off <<= 1) {
        int y = __shfl_up(x, off, 64);
        if (lane >= off) x += y;
    }
    int run = x - s;
    #pragma unroll
    for (int t = 0; t < PT; t++) {
        int i = lane * PT + t;
        if (i < B) { bucketPtr[i] = run; bucketCursor[i] = run; }
        run += v[t];
    }
    if (lane == 63) bucketPtr[B] = x;
    if (lane == 0) rowPtr[N] = E;
}

__global__ __launch_bounds__(256) void bucket_scatter_k(const int* __restrict__ src,
                                                        const int* __restrict__ dst,
                                                        int* __restrict__ bucketCursor,
                                                        int* __restrict__ ebuf,
                                                        int E, int B) {
    __shared__ int cnt[BMAX];
    __shared__ int base[BMAX];
    __shared__ int cur[BMAX];
    for (int i = threadIdx.x; i < B; i += 256) { cnt[i] = 0; cur[i] = 0; }
    __syncthreads();
    int cbase = blockIdx.x * CHUNK;
    int d[EPT];
    #pragma unroll
    for (int t = 0; t < EPT; t++) {
        int e = cbase + t * 256 + threadIdx.x;
        d[t] = (e < E) ? dst[e] : -1;
        if (d[t] >= 0) atomicAdd(&cnt[d[t] >> BSHIFT], 1);
    }
    __syncthreads();
    for (int i = threadIdx.x; i < B; i += 256)
        if (cnt[i] > 0) base[i] = atomicAdd(&bucketCursor[i], cnt[i]);
    __syncthreads();
    #pragma unroll
    for (int t = 0; t < EPT; t++) {
        int e = cbase + t * 256 + threadIdx.x;
        if (d[t] >= 0) {
            int b = d[t] >> BSHIFT;
            int c = atomicAdd(&cur[b], 1);
            int pack = (src[e] & 0xFFFF) | ((d[t] & (BNODES - 1)) << 16);
            ebuf[base[b] + c] = pack;
        }
    }
}

__global__ __launch_bounds__(256) void csr_build_k(const int* __restrict__ ebuf,
                                                   const int* __restrict__ bucketPtr,
                                                   int* __restrict__ rowPtr,
                                                   float* __restrict__ dinv,
                                                   int* __restrict__ srcSorted,
                                                   int N) {
    __shared__ int deg[BNODES];
    __shared__ int rp[BNODES + 1];
    __shared__ int cur[BNODES];
    __shared__ int stage[CAP];
    int b = blockIdx.x;
    int nodeBase = b << BSHIFT;
    int nNodes = min(BNODES, N - nodeBase);
    int eBase = bucketPtr[b];
    int eCnt = bucketPtr[b + 1] - eBase;
    for (int i = threadIdx.x; i < BNODES; i += 256) deg[i] = 0;
    __syncthreads();
    for (int i = threadIdx.x; i < eCnt; i += 256)
        atomicAdd(&deg[(ebuf[eBase + i] >> 16) & (BNODES - 1)], 1);
    __syncthreads();
    if (threadIdx.x < 64) {
        int lane = threadIdx.x;
        int d0 = deg[2 * lane], d1 = deg[2 * lane + 1];
        int s = d0 + d1;
        int x = s;
        #pragma unroll
        for (int off = 1; off < 64; off <<= 1) {
            int y = __shfl_up(x, off, 64);
            if (lane >= off) x += y;
        }
        int ex = x - s;
        rp[2 * lane] = ex;
        rp[2 * lane + 1] = ex + d0;
        cur[2 * lane] = ex;
        cur[2 * lane + 1] = ex + d0;
        if (lane == 63) rp[BNODES] = x;
    }
    __syncthreads();
    for (int j = threadIdx.x; j < nNodes; j += 256) {
        rowPtr[nodeBase + j] = eBase + rp[j];
        int dg = deg[j];
        dinv[nodeBase + j] = rsqrtf((float)(dg > 1 ? dg : 1));
    }
    if (eCnt <= CAP) {
        for (int i = threadIdx.x; i < eCnt; i += 256) {
            int p = ebuf[eBase + i];
            int ld = (p >> 16) & (BNODES - 1);
            int pos = atomicAdd(&cur[ld], 1);
            stage[pos] = p & 0xFFFF;
        }
        __syncthreads();
        for (int i = threadIdx.x; i < eCnt; i += 256)
            srcSorted[eBase + i] = stage[i];
    } else {
        for (int i = threadIdx.x; i < eCnt; i += 256) {
            int p = ebuf[eBase + i];
            int ld = (p >> 16) & (BNODES - 1);
            int pos = atomicAdd(&cur[ld], 1);
            srcSorted[eBase + pos] = p & 0xFFFF;
        }
    }
}

// ----------------------------- dense1 --------------------------------------
// Thread per node, AoS in/out, LDS-bounced contiguous output writes.

#define D1_BLK 128
#define D1_PAD 68

__global__ __launch_bounds__(D1_BLK) void dense1_k(const float* __restrict__ Xg,
                                                   const float* __restrict__ W1,
                                                   const float* __restrict__ b1,
                                                   float* __restrict__ h1, int N) {
    __shared__ float lds[D1_BLK * D1_PAD];
    int n0 = blockIdx.x * D1_BLK;
    int n = n0 + threadIdx.x;
    bool act = (n < N);
    const float4* W = (const float4*)W1;
    const float4* B = (const float4*)b1;
    float4 acc[16];
    #pragma unroll
    for (int j = 0; j < 16; j++) acc[j] = B[j];
    if (act) {
        const float4* X = (const float4*)Xg + (size_t)n * 32;
        float4 a = X[0];
        #pragma unroll 1
        for (int kc = 0; kc < 32; kc++) {
            float4 an = a;
            if (kc + 1 < 32) an = X[kc + 1];
            const float4* wrow = W + kc * 64;
            #pragma unroll
            for (int j = 0; j < 16; j++) {
                fma4(acc[j], a.x, wrow[j]);
                fma4(acc[j], a.y, wrow[16 + j]);
                fma4(acc[j], a.z, wrow[32 + j]);
                fma4(acc[j], a.w, wrow[48 + j]);
            }
            a = an;
        }
    }
    float* myrow = &lds[threadIdx.x * D1_PAD];
    #pragma unroll
    for (int j = 0; j < 16; j++) {
        float4 v = acc[j];
        *(float4*)&myrow[4 * j] = make_float4(fmaxf(v.x, 0.f), fmaxf(v.y, 0.f),
                                              fmaxf(v.z, 0.f), fmaxf(v.w, 0.f));
    }
    __syncthreads();
    float4* o4 = (float4*)h1;
    #pragma unroll
    for (int r = 0; r < 16; r++) {
        int idx = r * D1_BLK + threadIdx.x;
        int row = idx >> 4, col = idx & 15;
        int gn = n0 + row;
        if (gn < N) o4[(size_t)gn * 16 + col] = *(float4*)&lds[row * D1_PAD + col * 4];
    }
}

// ----------------------------- dense2res -----------------------------------
// Thread per node. Outputs h (fp32), hs (=f16(h*dinv)), res via LDS bounce;
// th = h.Wattn.

#define D2_BLK 128
#define D2_PAD 68

__global__ __launch_bounds__(D2_BLK) void dense2res_k(const float* __restrict__ h1,
                                                      const float* __restrict__ W2,
                                                      const float* __restrict__ b2,
                                                      const float* __restrict__ Wres,
                                                      const float* __restrict__ bres,
                                                      const float* __restrict__ Wattn,
                                                      const float* __restrict__ dinv,
                                                      float* __restrict__ hg,
                                                      float2* __restrict__ hs2,
                                                      float* __restrict__ resg,
                                                      float* __restrict__ thv, int N) {
    __shared__ float lds[D2_BLK * D2_PAD];
    int n0 = blockIdx.x * D2_BLK;
    int n = n0 + threadIdx.x;
    bool act = (n < N);
    const float4* W = (const float4*)W2;
    const float4* B = (const float4*)b2;
    float4 acc[16];
    #pragma unroll
    for (int j = 0; j < 16; j++) acc[j] = B[j];
    if (act) {
        const float4* X = (const float4*)h1 + (size_t)n * 16;
        float4 a = X[0];
        #pragma unroll 1
        for (int kc = 0; kc < 16; kc++) {
            float4 an = a;
            if (kc + 1 < 16) an = X[kc + 1];
            const float4* wrow = W + kc * 64;
            #pragma unroll
            for (int j = 0; j < 16; j++) {
                fma4(acc[j], a.x, wrow[j]);
                fma4(acc[j], a.y, wrow[16 + j]);
                fma4(acc[j], a.z, wrow[32 + j]);
                fma4(acc[j], a.w, wrow[48 + j]);
            }
            a = an;
        }
    }
    // relu; stage h; attention score
    const float4* Wa = (const float4*)Wattn;
    float th = 0.f;
    float* myrow = &lds[threadIdx.x * D2_PAD];
    #pragma unroll
    for (int j = 0; j < 16; j++) {
        float4 v = acc[j];
        v.x = fmaxf(v.x, 0.f); v.y = fmaxf(v.y, 0.f);
        v.z = fmaxf(v.z, 0.f); v.w = fmaxf(v.w, 0.f);
        acc[j] = v;
        *(float4*)&myrow[4 * j] = v;
        float4 w = Wa[j];
        th += v.x * w.x + v.y * w.y + v.z * w.z + v.w * w.w;
    }
    if (act) thv[n] = th;
    __syncthreads();
    // coop contiguous writes of h (fp32) and hs (f16 packed)
    float4* h4 = (float4*)hg;
    #pragma unroll
    for (int r = 0; r < 16; r++) {
        int idx = r * D2_BLK + threadIdx.x;
        int row = idx >> 4, col = idx & 15;
        int gn = n0 + row;
        if (gn < N) {
            float4 v = *(float4*)&lds[row * D2_PAD + col * 4];
            h4[(size_t)gn * 16 + col] = v;
            float di = dinv[gn];
            hs2[(size_t)gn * 16 + col] =
                pack_half4(v.x * di, v.y * di, v.z * di, v.w * di);
        }
    }
    // res = h @ Wres + bres (h still in regs)
    const float4* WR = (const float4*)Wres;
    const float4* BR = (const float4*)bres;
    float4 acc2[16];
    #pragma unroll
    for (int j = 0; j < 16; j++) acc2[j] = BR[j];
    #pragma unroll 1
    for (int kc = 0; kc < 16; kc++) {
        float4 a2 = acc[kc];
        const float4* wrow = WR + kc * 64;
        #pragma unroll
        for (int j = 0; j < 16; j++) {
            fma4(acc2[j], a2.x, wrow[j]);
            fma4(acc2[j], a2.y, wrow[16 + j]);
            fma4(acc2[j], a2.z, wrow[32 + j]);
            fma4(acc2[j], a2.w, wrow[48 + j]);
        }
    }
    __syncthreads();   // h/hs coop reads done before overwrite
    #pragma unroll
    for (int j = 0; j < 16; j++) *(float4*)&myrow[4 * j] = acc2[j];
    __syncthreads();
    float4* r4 = (float4*)resg;
    #pragma unroll
    for (int r = 0; r < 16; r++) {
        int idx = r * D2_BLK + threadIdx.x;
        int row = idx >> 4, col = idx & 15;
        int gn = n0 + row;
        if (gn < N) r4[(size_t)gn * 16 + col] = *(float4*)&lds[row * D2_PAD + col * 4];
    }
}

// ----------------------------- SPMM (spmm1) --------------------------------
// Wave per node (4/block). 16 lanes per f16 row (float2 loads), 4 chains,
// fp32 accum. Outputs u1 (fp32 AoS), u1s (f16), ta = u1.Wattn.

__global__ __launch_bounds__(256) void spmm_k(const float2* __restrict__ xs,
                                              const int* __restrict__ srcs,
                                              const int* __restrict__ rowPtr,
                                              const float* __restrict__ dinv,
                                              const float* __restrict__ Wattn,
                                              float4* __restrict__ u,
                                              float2* __restrict__ us,
                                              float* __restrict__ tav, int N) {
    int node = (blockIdx.x * 256 + threadIdx.x) >> 6;
    if (node >= N) return;
    int lane = threadIdx.x & 63;
    int sub = lane >> 4;
    int q = lane & 15;
    int s0 = rowPtr[node], s1 = rowPtr[node + 1];
    float4 a0 = make_float4(0.f, 0.f, 0.f, 0.f);
    float4 a1 = a0, a2 = a0, a3 = a0;
    int i = s0 + sub;
    for (; i + 12 < s1; i += 16) {
        int sA = srcs[i];
        int sB = srcs[i + 4];
        int sC = srcs[i + 8];
        int sD = srcs[i + 12];
        float2 vA = xs[(size_t)sA * 16 + q];
        float2 vB = xs[(size_t)sB * 16 + q];
        float2 vC = xs[(size_t)sC * 16 + q];
        float2 vD = xs[(size_t)sD * 16 + q];
        acch4(a0, vA); acch4(a1, vB); acch4(a2, vC); acch4(a3, vD);
    }
    for (; i + 4 < s1; i += 8) {
        int sA = srcs[i];
        int sB = srcs[i + 4];
        float2 vA = xs[(size_t)sA * 16 + q];
        float2 vB = xs[(size_t)sB * 16 + q];
        acch4(a0, vA); acch4(a1, vB);
    }
    if (i < s1) {
        float2 vA = xs[(size_t)srcs[i] * 16 + q];
        acch4(a0, vA);
    }
    a0.x += a1.x + a2.x + a3.x;
    a0.y += a1.y + a2.y + a3.y;
    a0.z += a1.z + a2.z + a3.z;
    a0.w += a1.w + a2.w + a3.w;
    #pragma unroll
    for (int m = 16; m < 64; m <<= 1) {
        a0.x += __shfl_xor(a0.x, m, 64);
        a0.y += __shfl_xor(a0.y, m, 64);
        a0.z += __shfl_xor(a0.z, m, 64);
        a0.w += __shfl_xor(a0.w, m, 64);
    }
    if (sub == 0) {
        float di = dinv[node];
        float4 r = make_float4(a0.x * di, a0.y * di, a0.z * di, a0.w * di);
        u[(size_t)node * 16 + q] = r;
        us[(size_t)node * 16 + q] =
            pack_half4(r.x * di, r.y * di, r.z * di, r.w * di);
        float4 w = ((const float4*)Wattn)[q];
        float p = r.x * w.x + r.y * w.y + r.z * w.z + r.w * w.w;
        #pragma unroll
        for (int m = 1; m < 16; m <<= 1) p += __shfl_xor(p, m, 64);
        if (lane == 0) tav[node] = p;
    }
}

// ----------------------------- fused spmm2 + tail --------------------------
// Wave per node (4/block), NO block barrier: each wave's LDS slice is
// wave-private (write + read by the same wave; ordered by lgkmcnt).
// Dense GEMVs use v_readlane broadcasts (VALU, operand in SGPR) instead of
// ds_bpermute, freeing the LDS pipe.

#define TL_PAD 68

__global__ __launch_bounds__(256) void tail_k(const float2* __restrict__ u1s,
                                              const int* __restrict__ srcs,
                                              const int* __restrict__ rowPtr,
                                              const float* __restrict__ dinv,
                                              const float* __restrict__ hg,
                                              const float* __restrict__ u1g,
                                              const float* __restrict__ resg,
                                              const float* __restrict__ thv,
                                              const float* __restrict__ tav,
                                              const float* __restrict__ Wattn,
                                              const float* __restrict__ battn,
                                              const float* __restrict__ Wf1,
                                              const float* __restrict__ bf1,
                                              const float* __restrict__ Wf2,
                                              const float* __restrict__ bf2,
                                              const float* __restrict__ W3,
                                              const float* __restrict__ b3,
                                              const float* __restrict__ W4,
                                              const float* __restrict__ b4,
                                              float2* __restrict__ out, int N) {
    __shared__ float lds[4 * TL_PAD];
    int w = threadIdx.x >> 6;
    int lane = threadIdx.x & 63;
    int node = blockIdx.x * 4 + w;
    if (node >= N) return;
    int sub = lane >> 4, q = lane & 15;
    {
        int s0 = rowPtr[node], s1 = rowPtr[node + 1];
        float4 a0 = make_float4(0.f, 0.f, 0.f, 0.f);
        float4 a1 = a0, a2 = a0, a3 = a0;
        int i = s0 + sub;
        for (; i + 12 < s1; i += 16) {
            int sA = srcs[i];
            int sB = srcs[i + 4];
            int sC = srcs[i + 8];
            int sD = srcs[i + 12];
            float2 vA = u1s[(size_t)sA * 16 + q];
            float2 vB = u1s[(size_t)sB * 16 + q];
            float2 vC = u1s[(size_t)sC * 16 + q];
            float2 vD = u1s[(size_t)sD * 16 + q];
            acch4(a0, vA); acch4(a1, vB); acch4(a2, vC); acch4(a3, vD);
        }
        for (; i + 4 < s1; i += 8) {
            int sA = srcs[i];
            int sB = srcs[i + 4];
            float2 vA = u1s[(size_t)sA * 16 + q];
            float2 vB = u1s[(size_t)sB * 16 + q];
            acch4(a0, vA); acch4(a1, vB);
        }
        if (i < s1) {
            float2 vA = u1s[(size_t)srcs[i] * 16 + q];
            acch4(a0, vA);
        }
        a0.x += a1.x + a2.x + a3.x;
        a0.y += a1.y + a2.y + a3.y;
        a0.z += a1.z + a2.z + a3.z;
        a0.w += a1.w + a2.w + a3.w;
        #pragma unroll
        for (int m = 16; m < 64; m <<= 1) {
            a0.x += __shfl_xor(a0.x, m, 64);
            a0.y += __shfl_xor(a0.y, m, 64);
            a0.z += __shfl_xor(a0.z, m, 64);
            a0.w += __shfl_xor(a0.w, m, 64);
        }
        if (sub == 0) {
            float di = dinv[node];
            *(float4*)&lds[w * TL_PAD + q * 4] =
                make_float4(a0.x * di, a0.y * di, a0.z * di, a0.w * di);
        }
    }
    // wave-private LDS: same wave wrote it; lgkmcnt orders write->read.
    float u2j = lds[w * TL_PAD + lane];                  // feature j = lane
    float hj = hg[(size_t)node * 64 + lane];
    float u1j = u1g[(size_t)node * 64 + lane];
    float resj = resg[(size_t)node * 64 + lane];
    // tb = u2 . Wattn
    float tb = u2j * Wattn[lane];
    #pragma unroll
    for (int m = 1; m < 64; m <<= 1) tb += __shfl_xor(tb, m, 64);
    float th = thv[node], ta = tav[node], ba = battn[0];
    float s0 = 0.75f * th + 1.5f * ta + 0.75f * tb + ba;
    float s1 = 1.5f * th - 1.5f * tb + ba;
    float s2 = 0.75f * th - 1.5f * ta + 0.75f * tb + ba;
    float mx = fmaxf(s0, fmaxf(s1, s2));
    float e0 = expf(s0 - mx), e1 = expf(s1 - mx), e2 = expf(s2 - mx);
    float inv = 1.f / (e0 + e1 + e2);
    float w0 = e0 * inv, w1 = e1 * inv, w2 = e2 * inv;
    float ca = 0.75f * w0 + 1.5f * w1 + 0.75f * w2;
    float cb = 1.5f * (w0 - w2);
    float cc = 0.75f * w0 - 1.5f * w1 + 0.75f * w2;
    float afj = ca * hj + cb * u1j + cc * u2j;
    // t = relu([af | h] @ Wf1 + bf1)  (wave-GEMV, readlane-broadcast inputs)
    float t = bf1[lane];
    #pragma unroll 4
    for (int k = 0; k < 64; k++) {
        float afk = bcast(afj, k);
        float hk = bcast(hj, k);
        t += afk * Wf1[k * 64 + lane] + hk * Wf1[(64 + k) * 64 + lane];
    }
    t = fmaxf(t, 0.f);
    float fwacc = t * Wf2[lane];
    #pragma unroll
    for (int m = 1; m < 64; m <<= 1) fwacc += __shfl_xor(fwacc, m, 64);
    float fw = 1.f / (1.f + expf(-(fwacc + bf2[0])));
    // fused = 0.1*fw*af + (1-fw)*h + 0.8*res   (mean_fused == h exactly)
    float fj = 0.1f * fw * afj + (1.f - fw) * hj + 0.8f * resj;
    float g = b3[lane];
    #pragma unroll 4
    for (int k = 0; k < 64; k++) {
        float fk = bcast(fj, k);
        g += fk * W3[k * 64 + lane];
    }
    g = fmaxf(g, 0.f);
    float2 w4 = ((const float2*)W4)[lane];
    float l0 = g * w4.x, l1 = g * w4.y;
    #pragma unroll
    for (int m = 1; m < 64; m <<= 1) {
        l0 += __shfl_xor(l0, m, 64);
        l1 += __shfl_xor(l1, m, 64);
    }
    if (lane == 0) out[node] = make_float2(l0 + b4[0], l1 + b4[1]);
}

// ----------------------------- launch --------------------------------------

extern "C" void kernel_launch(void* const* d_in, const int* in_sizes, int n_in,
                              void* d_out, int out_size, void* d_ws, size_t ws_size,
                              hipStream_t stream) {
    const float* in_feat = (const float*)d_in[0];
    const int*   src     = (const int*)d_in[1];
    const int*   dst     = (const int*)d_in[2];
    const float* W1   = (const float*)d_in[3];
    const float* b1   = (const float*)d_in[4];
    const float* W2   = (const float*)d_in[5];
    const float* b2   = (const float*)d_in[6];
    const float* Wres = (const float*)d_in[7];
    const float* bres = (const float*)d_in[8];
    const float* Wattn = (const float*)d_in[9];
    const float* battn = (const float*)d_in[10];
    const float* Wf1  = (const float*)d_in[11];
    const float* bf1  = (const float*)d_in[12];
    const float* Wf2  = (const float*)d_in[13];
    const float* bf2  = (const float*)d_in[14];
    const float* W3   = (const float*)d_in[15];
    const float* b3   = (const float*)d_in[16];
    const float* W4   = (const float*)d_in[17];
    const float* b4   = (const float*)d_in[18];

    const int N = in_sizes[0] / 128;
    const int E = in_sizes[1];
    const int B = (N + BNODES - 1) >> BSHIFT;

    char* p = (char*)d_ws;
    auto take = [&](size_t bytes) -> char* {
        char* r = p;
        p += (bytes + 255) & ~(size_t)255;
        return r;
    };
    int*   bucketCount  = (int*)take((size_t)(B + 1) * 4);
    int*   bucketPtr    = (int*)take((size_t)(B + 1) * 4);
    int*   bucketCursor = (int*)take((size_t)(B + 1) * 4);
    int*   rowPtr       = (int*)take((size_t)(N + 1) * 4);
    float* dinv         = (float*)take((size_t)N * 4);
    int*   srcSorted    = (int*)take((size_t)E * 4);
    float* thv          = (float*)take((size_t)N * 4);
    float* tav          = (float*)take((size_t)N * 4);
    float* h1  = (float*)take((size_t)N * 256);
    float* h   = (float*)take((size_t)N * 256);
    float* hs  = (float*)take((size_t)N * 128);   // f16 packed, 64 halves/row
    float* res = (float*)take((size_t)N * 256);
    float* u1  = (float*)take((size_t)N * 256);
    float* u1s = (float*)take((size_t)N * 128);   // f16 packed
    int*   ebuf = (int*)h1;   // dead before dense1 writes h1 (stream order)

    int eb = (E + CHUNK - 1) / CHUNK;
    int d1b = (N + D1_BLK - 1) / D1_BLK;
    int d2b = (N + D2_BLK - 1) / D2_BLK;
    int spb = (N * 64 + 255) / 256;
    int tlb = (N + 3) / 4;

    hipMemsetAsync(bucketCount, 0, (size_t)B * 4, stream);
    bucket_count_k<<<eb, 256, 0, stream>>>(dst, bucketCount, E, B);
    bucket_scan_k<<<1, 64, 0, stream>>>(bucketCount, bucketPtr, bucketCursor,
                                        rowPtr, B, N, E);
    bucket_scatter_k<<<eb, 256, 0, stream>>>(src, dst, bucketCursor, ebuf, E, B);
    csr_build_k<<<B, 256, 0, stream>>>(ebuf, bucketPtr, rowPtr, dinv, srcSorted, N);

    dense1_k<<<d1b, D1_BLK, 0, stream>>>(in_feat, W1, b1, h1, N);
    dense2res_k<<<d2b, D2_BLK, 0, stream>>>(h1, W2, b2, Wres, bres, Wattn, dinv,
                                            h, (float2*)hs, res, thv, N);

    spmm_k<<<spb, 256, 0, stream>>>((const float2*)hs, srcSorted, rowPtr, dinv,
                                    Wattn, (float4*)u1, (float2*)u1s, tav, N);

    tail_k<<<tlb, 256, 0, stream>>>((const float2*)u1s, srcSorted, rowPtr, dinv,
                                    h, u1, res, thv, tav, Wattn, battn,
                                    Wf1, bf1, Wf2, bf2, W3, b3, W4, b4,
                                    (float2*)d_out, N);
}